// Round 1
// baseline (227.515 us; speedup 1.0000x reference)
//
#include <hip/hip_runtime.h>
#include <stdint.h>

#define N_NODES 50000
#define DEG 16
#define IN_F 256
#define HEADS 4
#define OUT_F 64
#define HF 256          // HEADS * OUT_F
#define NEG_SLOPE 0.2f

typedef short bf16x8 __attribute__((ext_vector_type(8)));
typedef float f32x4 __attribute__((ext_vector_type(4)));

__device__ __forceinline__ unsigned short f2b(float f) {
    union { float f; uint32_t i; } v; v.f = f;
    uint32_t r = v.i + 0x7FFFu + ((v.i >> 16) & 1u);   // RTNE
    return (unsigned short)(r >> 16);
}
__device__ __forceinline__ float b2f(unsigned short u) {
    union { uint32_t i; float f; } v; v.i = ((uint32_t)u) << 16;
    return v.f;
}

__device__ __forceinline__ bf16x8 load_cvt8(const float* __restrict__ p) {
    const float4* p4 = (const float4*)p;
    float4 f0 = p4[0];
    float4 f1 = p4[1];
    bf16x8 a;
    a[0] = (short)f2b(f0.x); a[1] = (short)f2b(f0.y);
    a[2] = (short)f2b(f0.z); a[3] = (short)f2b(f0.w);
    a[4] = (short)f2b(f1.x); a[5] = (short)f2b(f1.y);
    a[6] = (short)f2b(f1.z); a[7] = (short)f2b(f1.w);
    return a;
}

// Kernel 1: h[N][256] (bf16) = x[N][256] @ W[256][256]^T
// Block = 256 threads (4 waves). Block tile: 64 rows x 256 cols.
// Wave w computes cols [64w, 64w+64): 4x4 grid of 16x16x32 MFMA frags.
__global__ __launch_bounds__(256) void proj_gemm(
    const float* __restrict__ x, const float* __restrict__ W,
    unsigned short* __restrict__ h)
{
    const int lane = threadIdx.x & 63;
    const int wave = threadIdx.x >> 6;
    const int m0 = blockIdx.x * 64;
    const int ncol0 = wave * 64;
    const int ar = lane & 15;   // A row / B col within 16-frag
    const int kg = lane >> 4;   // k-group: 8 consecutive k elems

    f32x4 acc[4][4];
    #pragma unroll
    for (int i = 0; i < 4; i++)
        #pragma unroll
        for (int j = 0; j < 4; j++)
            #pragma unroll
            for (int k = 0; k < 4; k++) acc[i][j][k] = 0.0f;

    #pragma unroll
    for (int kc = 0; kc < IN_F; kc += 32) {
        const int kbase = kc + kg * 8;
        bf16x8 afrag[4], bfrag[4];
        #pragma unroll
        for (int mi = 0; mi < 4; mi++) {
            int row = m0 + mi * 16 + ar;
            if (row >= N_NODES) row = N_NODES - 1;   // clamp; result unused
            afrag[mi] = load_cvt8(x + (size_t)row * IN_F + kbase);
        }
        #pragma unroll
        for (int ni = 0; ni < 4; ni++) {
            int o = ncol0 + ni * 16 + ar;
            bfrag[ni] = load_cvt8(W + (size_t)o * IN_F + kbase);
        }
        #pragma unroll
        for (int mi = 0; mi < 4; mi++)
            #pragma unroll
            for (int ni = 0; ni < 4; ni++)
                acc[mi][ni] = __builtin_amdgcn_mfma_f32_16x16x32_bf16(
                    afrag[mi], bfrag[ni], acc[mi][ni], 0, 0, 0);
    }

    // D layout: col = lane&15, row = (lane>>4)*4 + reg
    #pragma unroll
    for (int mi = 0; mi < 4; mi++) {
        #pragma unroll
        for (int reg = 0; reg < 4; reg++) {
            const int row = m0 + mi * 16 + kg * 4 + reg;
            if (row < N_NODES) {
                #pragma unroll
                for (int ni = 0; ni < 4; ni++) {
                    const int colv = ncol0 + ni * 16 + ar;
                    h[(size_t)row * HF + colv] = f2b(acc[mi][ni][reg]);
                }
            }
        }
    }
}

// Kernel 2: a_i[N][4], a_j[N][4] from h, att_i, att_j. One wave per node.
__global__ __launch_bounds__(256) void att_coef(
    const unsigned short* __restrict__ h,
    const float* __restrict__ atti, const float* __restrict__ attj,
    float* __restrict__ a_i, float* __restrict__ a_j)
{
    const int lane = threadIdx.x & 63;
    const int node = blockIdx.x * 4 + (threadIdx.x >> 6);
    if (node >= N_NODES) return;
    const int head = lane >> 4;
    const int fb = (lane & 15) * 4;   // feature base within head
    // lane*4 == head*64 + fb
    ushort4 hv = *(const ushort4*)(h + (size_t)node * HF + lane * 4);
    float v0 = b2f(hv.x), v1 = b2f(hv.y), v2 = b2f(hv.z), v3 = b2f(hv.w);
    const float* ai = atti + head * OUT_F + fb;
    const float* aj = attj + head * OUT_F + fb;
    float pi = v0 * ai[0] + v1 * ai[1] + v2 * ai[2] + v3 * ai[3];
    float pj = v0 * aj[0] + v1 * aj[1] + v2 * aj[2] + v3 * aj[3];
    #pragma unroll
    for (int off = 1; off < 16; off <<= 1) {
        pi += __shfl_xor(pi, off);
        pj += __shfl_xor(pj, off);
    }
    if ((lane & 15) == 0) {
        a_i[node * HEADS + head] = pi;
        a_j[node * HEADS + head] = pj;
    }
}

// Kernel 3: per-node softmax over 16 edges + weighted gather-sum.
// One wave per node. lane -> (head = l>>4, edge j = l&15) for attention,
// and output elements [4l, 4l+4) (head = l>>4 consistent) for aggregation.
__global__ __launch_bounds__(256) void gat_agg(
    const unsigned short* __restrict__ h,
    const float* __restrict__ a_i, const float* __restrict__ a_j,
    const int* __restrict__ col, float* __restrict__ out)
{
    const int lane = threadIdx.x & 63;
    const int node = blockIdx.x * 4 + (threadIdx.x >> 6);
    if (node >= N_NODES) return;
    const int head = lane >> 4;
    const int j = lane & 15;

    const int src = col[node * DEG + j];
    float e = a_i[node * HEADS + head] + a_j[src * HEADS + head];
    e = (e > 0.0f) ? e : NEG_SLOPE * e;
    float m = e;
    #pragma unroll
    for (int off = 1; off < 16; off <<= 1) m = fmaxf(m, __shfl_xor(m, off));
    float p = __expf(e - m);
    float s = p;
    #pragma unroll
    for (int off = 1; off < 16; off <<= 1) s += __shfl_xor(s, off);
    const float alpha = p / (s + 1e-16f);

    float acc0 = 0.f, acc1 = 0.f, acc2 = 0.f, acc3 = 0.f;
    const int myoff = lane * 4;
    #pragma unroll
    for (int jj = 0; jj < 16; jj++) {
        const int sj = __shfl(src, jj);
        const float al = __shfl(alpha, (lane & 48) + jj);
        ushort4 hv = *(const ushort4*)(h + (size_t)sj * HF + myoff);
        acc0 += al * b2f(hv.x);
        acc1 += al * b2f(hv.y);
        acc2 += al * b2f(hv.z);
        acc3 += al * b2f(hv.w);
    }
    float4 o;
    o.x = acc0; o.y = acc1; o.z = acc2; o.w = acc3;
    *(float4*)(out + (size_t)node * HF + myoff) = o;
}

extern "C" void kernel_launch(void* const* d_in, const int* in_sizes, int n_in,
                              void* d_out, int out_size, void* d_ws, size_t ws_size,
                              hipStream_t stream) {
    const float* x      = (const float*)d_in[0];
    // d_in[1] = row_id, d_in[2] = row_ptr: implied by consistent CSR, unused.
    const int*   col_id = (const int*)d_in[3];
    const float* W      = (const float*)d_in[4];
    const float* atti   = (const float*)d_in[5];
    const float* attj   = (const float*)d_in[6];
    float* out = (float*)d_out;

    unsigned short* h = (unsigned short*)d_ws;                       // 25.6 MB
    float* a_i = (float*)((char*)d_ws + (size_t)N_NODES * HF * 2);   // 800 KB
    float* a_j = a_i + (size_t)N_NODES * HEADS;                      // 800 KB

    proj_gemm<<<(N_NODES + 63) / 64, 256, 0, stream>>>(x, W, h);
    att_coef<<<(N_NODES + 3) / 4, 256, 0, stream>>>(h, atti, attj, a_i, a_j);
    gat_agg<<<(N_NODES + 3) / 4, 256, 0, stream>>>(h, a_i, a_j, col_id, out);
}

// Round 2
// 191.258 us; speedup vs baseline: 1.1896x; 1.1896x over previous
//
#include <hip/hip_runtime.h>
#include <hip/hip_bf16.h>
#include <stdint.h>

#define N_NODES 50000
#define DEG 16
#define IN_F 256
#define HEADS 4
#define OUT_F 64
#define HF 256          // HEADS * OUT_F
#define NEG_SLOPE 0.2f

typedef short bf16x8 __attribute__((ext_vector_type(8)));
typedef float f32x4 __attribute__((ext_vector_type(4)));

__device__ __forceinline__ unsigned short f2b(float f) {
    __hip_bfloat16 b = __float2bfloat16(f);
    return *(unsigned short*)&b;
}
__device__ __forceinline__ float b2f(unsigned short u) {
    union { uint32_t i; float f; } v; v.i = ((uint32_t)u) << 16;
    return v.f;
}

// Kernel 0: W [256][256] fp32 -> bf16 (row-major unchanged). 32 blocks.
__global__ __launch_bounds__(256) void wprep(
    const float* __restrict__ W, unsigned short* __restrict__ Wb)
{
    const int i = (blockIdx.x * 256 + threadIdx.x) * 8;
    float4 f0 = ((const float4*)(W + i))[0];
    float4 f1 = ((const float4*)(W + i))[1];
    bf16x8 v;
    v[0] = (short)f2b(f0.x); v[1] = (short)f2b(f0.y);
    v[2] = (short)f2b(f0.z); v[3] = (short)f2b(f0.w);
    v[4] = (short)f2b(f1.x); v[5] = (short)f2b(f1.y);
    v[6] = (short)f2b(f1.z); v[7] = (short)f2b(f1.w);
    *(bf16x8*)(Wb + i) = v;
}

// Kernel 1: fused projection GEMM + attention-half reduction.
// h[N][256](bf16) = x@W^T ; a_i[N][4], a_j[N][4] from fp32 accumulators.
// Block = 256 thr (4 waves), tile 64 rows x 256 cols; wave w = head w (cols 64w..64w+63).
// x-tile staged once in LDS as bf16 with XOR chunk swizzle (c ^= row&7).
__global__ __launch_bounds__(256) void proj_fused(
    const float* __restrict__ x, const unsigned short* __restrict__ Wb,
    const float* __restrict__ atti, const float* __restrict__ attj,
    unsigned short* __restrict__ h,
    float* __restrict__ a_i, float* __restrict__ a_j)
{
    __shared__ unsigned short As[64 * 256];   // 32 KB bf16, swizzled 16B chunks

    const int tid  = threadIdx.x;
    const int lane = tid & 63;
    const int wave = tid >> 6;
    const int m0   = blockIdx.x * 64;

    // ---- stage x-tile: 2048 chunks of 16B (8 bf16); coalesced fp32 reads ----
    #pragma unroll
    for (int p = 0; p < 8; p++) {
        const int C   = p * 256 + tid;   // chunk id 0..2047
        const int row = C >> 5;          // 0..63
        const int c   = C & 31;          // chunk within row
        int grow = m0 + row;
        if (grow >= N_NODES) grow = N_NODES - 1;   // clamp OOB reads (unused rows)
        const float* src = x + (size_t)grow * IN_F + c * 8;
        float4 f0 = ((const float4*)src)[0];
        float4 f1 = ((const float4*)src)[1];
        bf16x8 v;
        v[0] = (short)f2b(f0.x); v[1] = (short)f2b(f0.y);
        v[2] = (short)f2b(f0.z); v[3] = (short)f2b(f0.w);
        v[4] = (short)f2b(f1.x); v[5] = (short)f2b(f1.y);
        v[6] = (short)f2b(f1.z); v[7] = (short)f2b(f1.w);
        const int sc = c ^ (row & 7);    // XOR swizzle
        *(bf16x8*)(As + row * 256 + sc * 8) = v;
    }
    __syncthreads();

    // ---- MFMA K-loop: 8 iters, all LDS + L2-hot W ----
    const int ar = lane & 15;    // A row / B col within fragment
    const int kg = lane >> 4;    // k-group (8 consecutive k)
    const int ncol0 = wave * 64;

    f32x4 acc[4][4];
    #pragma unroll
    for (int i = 0; i < 4; i++)
        #pragma unroll
        for (int j = 0; j < 4; j++)
            #pragma unroll
            for (int k = 0; k < 4; k++) acc[i][j][k] = 0.0f;

    #pragma unroll
    for (int kc8 = 0; kc8 < 8; kc8++) {
        const int kbase = kc8 * 32 + kg * 8;    // element k base
        const int cA    = kc8 * 4 + kg;         // 16B chunk within row
        bf16x8 afrag[4], bfrag[4];
        #pragma unroll
        for (int mi = 0; mi < 4; mi++) {
            const int row = mi * 16 + ar;
            const int sc  = cA ^ (row & 7);
            afrag[mi] = *(const bf16x8*)(As + row * 256 + sc * 8);
        }
        #pragma unroll
        for (int ni = 0; ni < 4; ni++) {
            const int o = ncol0 + ni * 16 + ar;
            bfrag[ni] = *(const bf16x8*)(Wb + (size_t)o * IN_F + kbase);
        }
        #pragma unroll
        for (int mi = 0; mi < 4; mi++)
            #pragma unroll
            for (int ni = 0; ni < 4; ni++)
                acc[mi][ni] = __builtin_amdgcn_mfma_f32_16x16x32_bf16(
                    afrag[mi], bfrag[ni], acc[mi][ni], 0, 0, 0);
    }

    // ---- epilogue: store h (bf16) + fused a_i/a_j reduction ----
    // D layout: col = ncol0 + ni*16 + ar, row = m0 + mi*16 + kg*4 + reg
    float ai_l[4], aj_l[4];
    #pragma unroll
    for (int ni = 0; ni < 4; ni++) {
        ai_l[ni] = atti[ncol0 + ni * 16 + ar];   // att_i flat [H*F]
        aj_l[ni] = attj[ncol0 + ni * 16 + ar];
    }
    #pragma unroll
    for (int mi = 0; mi < 4; mi++) {
        #pragma unroll
        for (int reg = 0; reg < 4; reg++) {
            const int row = m0 + mi * 16 + kg * 4 + reg;
            float pi = 0.f, pj = 0.f;
            #pragma unroll
            for (int ni = 0; ni < 4; ni++) {
                const float v = acc[mi][ni][reg];
                pi += v * ai_l[ni];
                pj += v * aj_l[ni];
            }
            #pragma unroll
            for (int off = 1; off < 16; off <<= 1) {
                pi += __shfl_xor(pi, off);
                pj += __shfl_xor(pj, off);
            }
            if (row < N_NODES) {
                #pragma unroll
                for (int ni = 0; ni < 4; ni++)
                    h[(size_t)row * HF + ncol0 + ni * 16 + ar] = f2b(acc[mi][ni][reg]);
                if (ar == 0) {
                    a_i[row * HEADS + wave] = pi;
                    a_j[row * HEADS + wave] = pj;
                }
            }
        }
    }
}

// Kernel 2: per-node softmax over 16 edges + weighted gather-sum.
__global__ __launch_bounds__(256) void gat_agg(
    const unsigned short* __restrict__ h,
    const float* __restrict__ a_i, const float* __restrict__ a_j,
    const int* __restrict__ col, float* __restrict__ out)
{
    const int lane = threadIdx.x & 63;
    const int node = blockIdx.x * 4 + (threadIdx.x >> 6);
    if (node >= N_NODES) return;
    const int head = lane >> 4;
    const int j = lane & 15;

    const int src = col[node * DEG + j];
    float e = a_i[node * HEADS + head] + a_j[src * HEADS + head];
    e = (e > 0.0f) ? e : NEG_SLOPE * e;
    float m = e;
    #pragma unroll
    for (int off = 1; off < 16; off <<= 1) m = fmaxf(m, __shfl_xor(m, off));
    float p = __expf(e - m);
    float s = p;
    #pragma unroll
    for (int off = 1; off < 16; off <<= 1) s += __shfl_xor(s, off);
    const float alpha = p / (s + 1e-16f);

    float acc0 = 0.f, acc1 = 0.f, acc2 = 0.f, acc3 = 0.f;
    const int myoff = lane * 4;
    #pragma unroll
    for (int jj = 0; jj < 16; jj++) {
        const int sj = __shfl(src, jj);
        const float al = __shfl(alpha, (lane & 48) + jj);
        ushort4 hv = *(const ushort4*)(h + (size_t)sj * HF + myoff);
        acc0 += al * b2f(hv.x);
        acc1 += al * b2f(hv.y);
        acc2 += al * b2f(hv.z);
        acc3 += al * b2f(hv.w);
    }
    float4 o;
    o.x = acc0; o.y = acc1; o.z = acc2; o.w = acc3;
    *(float4*)(out + (size_t)node * HF + myoff) = o;
}

extern "C" void kernel_launch(void* const* d_in, const int* in_sizes, int n_in,
                              void* d_out, int out_size, void* d_ws, size_t ws_size,
                              hipStream_t stream) {
    const float* x      = (const float*)d_in[0];
    // d_in[1] = row_id, d_in[2] = row_ptr: implied by consistent CSR, unused.
    const int*   col_id = (const int*)d_in[3];
    const float* W      = (const float*)d_in[4];
    const float* atti   = (const float*)d_in[5];
    const float* attj   = (const float*)d_in[6];
    float* out = (float*)d_out;

    unsigned short* h = (unsigned short*)d_ws;                        // 25.6 MB
    float* a_i = (float*)((char*)d_ws + (size_t)N_NODES * HF * 2);    // 800 KB
    float* a_j = a_i + (size_t)N_NODES * HEADS;                       // 800 KB
    unsigned short* Wb = (unsigned short*)(a_j + (size_t)N_NODES * HEADS); // 128 KB

    wprep<<<32, 256, 0, stream>>>(W, Wb);
    proj_fused<<<(N_NODES + 63) / 64, 256, 0, stream>>>(x, Wb, atti, attj, h, a_i, a_j);
    gat_agg<<<(N_NODES + 3) / 4, 256, 0, stream>>>(h, a_i, a_j, col_id, out);
}